// Round 4
// baseline (1874.427 us; speedup 1.0000x reference)
//
#include <hip/hip_runtime.h>
#include <math.h>
#include <stdint.h>

// Problem constants
#define BB   32     // batch
#define HB   16     // batch per block (b-split: 2 blocks per n-group)
#define NN   2048   // input capsules
#define KK   16     // input dim
#define CC   32     // output capsules
#define DD   32     // capsule dim
#define NCOL 1024   // CC*DD
#define NPB  8      // n per block -> 256 n-groups x 2 b-halves = 512 blocks (2/CU)
#define WT   (KK * NCOL)          // 16384 floats = one 64 KB W tile
#define OSZ  (BB * NCOL)          // 32768 floats = one full o/partial image
#define NGRP (NN / NPB)           // 256 partial images
#define NSLICE 8                  // reduce tree fan-in stage 1: 256 -> 8

// Ladder of lessons (R0..R3):
//  - 1024-thr blocks are hard-pinned at 64 VGPR; any structure needing more
//    spills catastrophically (R1: 86 MB, R2: 1.3 GB scratch round-trip).
//  - 512-thr + 148 KB LDS double-buffer (R3) = 1 block/CU: lockstep barriers
//    expose the full DMA latency every iter; per-CU DMA rate ~7 GB/s.
//    Cross-round data: per-CU staging throughput scales with co-resident
//    blocks/waves, NOT with schedule cleverness (R0 2 blk/CU: 11 GB/s/CU).
//  - W has NO intra-block reuse (each element used once per block; reuse is
//    only across the paired b-half block) -> LDS staging of W buys nothing.
// R4 (this): direct per-thread float4 W loads (perfectly coalesced: lanes
// cq, cq+1 read consecutive 16 B). No W LDS, no DMA, no vmcnt choreography,
// plain __syncthreads x2 per iter. LDS 12 KB -> 2 blocks/CU, 32 waves/CU of
// ordinary pipelined vector loads. Intra-block 4x bg-redundancy of W rows is
// served by L1/L2; cross-block (b-half) reuse by XCD-paired L2:
// ngrp = blk&255, bhalf = blk>>8 (blocks g and g+256 -> same XCD since
// 256%8==0; R0's blk>>1 pairing put pairs on DIFFERENT XCDs).
__global__ __launch_bounds__(1024)
void caps_stage(const float* __restrict__ u, const float* __restrict__ W,
                const float* __restrict__ onorm, float* __restrict__ part)
{
    __shared__ float ush[NPB * KK * HB];     // 8 KB: [n][k][b] all 8 n's
    __shared__ float logit_sh[HB * CC];      // 2 KB
    __shared__ float c_sh[HB * CC];          // 2 KB

    const int tid  = threadIdx.x;
    const int bg = tid >> 8;          // 0..3 -> 4 local b's each
    const int cq = tid & 255;         // col-quad 0..255
    const int i0 = cq >> 3;           // capsule 0..31
    const int jq = cq & 7;            // d-quad
    const int b0 = bg << 2;           // local b base
    const int c0 = cq << 2;           // col base

    const int ngrp  = blockIdx.x & 255;
    const int bhalf = blockIdx.x >> 8;
    const int n0    = ngrp * NPB;
    const int bbase = bhalf * HB;     // global b offset

    // prologue: stage u for this block (8 KB, transposed [n][k][b])
    for (int idx = tid; idx < NPB * KK * HB; idx += 1024) {
        const int n = idx >> 8, rem = idx & 255, k = rem >> 4, b = rem & 15;
        ush[idx] = u[(size_t)(bbase + b) * (NN * KK) + (size_t)(n0 + n) * KK + k];
    }
    __syncthreads();

    // per-thread W column base: W[n0][0][c0..c0+3]
    const float* wp = W + (size_t)n0 * WT + c0;

    float opart[4][4];
#pragma unroll
    for (int bb = 0; bb < 4; ++bb)
#pragma unroll
        for (int m = 0; m < 4; ++m) opart[bb][m] = 0.f;

    for (int nn = 0; nn < NPB; ++nn) {
        const float* un = &ush[nn << 8];

        float accU[4][4];
#pragma unroll
        for (int bb = 0; bb < 4; ++bb)
#pragma unroll
            for (int m = 0; m < 4; ++m) accU[bb][m] = 0.f;

#pragma unroll
        for (int k = 0; k < KK; ++k) {
            const float4 w  = *(const float4*)(wp + k * NCOL);     // global, coalesced
            const float4 ub = *(const float4*)&un[(k << 4) + b0];  // u[b0..b0+3][k]
            accU[0][0] = fmaf(ub.x, w.x, accU[0][0]);
            accU[0][1] = fmaf(ub.x, w.y, accU[0][1]);
            accU[0][2] = fmaf(ub.x, w.z, accU[0][2]);
            accU[0][3] = fmaf(ub.x, w.w, accU[0][3]);
            accU[1][0] = fmaf(ub.y, w.x, accU[1][0]);
            accU[1][1] = fmaf(ub.y, w.y, accU[1][1]);
            accU[1][2] = fmaf(ub.y, w.z, accU[1][2]);
            accU[1][3] = fmaf(ub.y, w.w, accU[1][3]);
            accU[2][0] = fmaf(ub.z, w.x, accU[2][0]);
            accU[2][1] = fmaf(ub.z, w.y, accU[2][1]);
            accU[2][2] = fmaf(ub.z, w.z, accU[2][2]);
            accU[2][3] = fmaf(ub.z, w.w, accU[2][3]);
            accU[3][0] = fmaf(ub.w, w.x, accU[3][0]);
            accU[3][1] = fmaf(ub.w, w.y, accU[3][1]);
            accU[3][2] = fmaf(ub.w, w.z, accU[3][2]);
            accU[3][3] = fmaf(ub.w, w.w, accU[3][3]);
        }
        wp += WT;   // next n's tile

        // ---- logits: dot with onorm (L2-resident), reduce over jq lanes ----
#pragma unroll
        for (int bb = 0; bb < 4; ++bb) {
            const float4 on4 = *(const float4*)(
                onorm + ((size_t)(bbase + b0 + bb) * CC + i0) * DD + (jq << 2));
            float p = accU[bb][0] * on4.x + accU[bb][1] * on4.y
                    + accU[bb][2] * on4.z + accU[bb][3] * on4.w;
            p += __shfl_xor(p, 1);
            p += __shfl_xor(p, 2);
            p += __shfl_xor(p, 4);
            if (jq == 0)
                logit_sh[(b0 + bb) * CC + i0] = p;
        }
        __syncthreads();   // (B) logits ready

        // ---- softmax over capsules: 512 threads, (b = tid>>5, cap = tid&31) ----
        if (tid < HB * CC) {
            const int b  = tid >> 5;
            const int ii = tid & 31;
            float l = logit_sh[b * CC + ii];
            float mx = l;
#pragma unroll
            for (int msk = 16; msk >= 1; msk >>= 1)
                mx = fmaxf(mx, __shfl_xor(mx, msk));
            const float e = __expf(l - mx);
            float sm = e;
#pragma unroll
            for (int msk = 16; msk >= 1; msk >>= 1)
                sm += __shfl_xor(sm, msk);
            c_sh[b * CC + ii] = e / sm;
        }
        __syncthreads();   // (C) c ready

        // ---- opart += c * U ----
#pragma unroll
        for (int bb = 0; bb < 4; ++bb) {
            const float cc = c_sh[(b0 + bb) * CC + i0];
#pragma unroll
            for (int m = 0; m < 4; ++m)
                opart[bb][m] = fmaf(cc, accU[bb][m], opart[bb][m]);
        }
    }

    // flush partials, coalesced float4 stores (this block's 16-b half)
    float* my = part + (size_t)ngrp * OSZ + (size_t)bbase * NCOL;
#pragma unroll
    for (int bb = 0; bb < 4; ++bb) {
        float4 v;
        v.x = opart[bb][0]; v.y = opart[bb][1];
        v.z = opart[bb][2]; v.w = opart[bb][3];
        *(float4*)&my[(b0 + bb) * NCOL + c0] = v;
    }
}

// Level-1 reduce: 256 partial images -> NSLICE slice images (32 each).
__global__ __launch_bounds__(256) void caps_reduce1(
    const float* __restrict__ part, float* __restrict__ ws2)
{
    const int gid   = blockIdx.x * 256 + threadIdx.x;     // 0..65535
    const int slice = gid >> 13;                          // 0..7
    const int q     = gid & 8191;                         // col-quad
    float4 acc = make_float4(0.f, 0.f, 0.f, 0.f);
    const float* p = part + ((size_t)slice * 32) * OSZ + (q << 2);
#pragma unroll 8
    for (int j = 0; j < 32; ++j) {
        const float4 v = *(const float4*)(p + (size_t)j * OSZ);
        acc.x += v.x; acc.y += v.y; acc.z += v.z; acc.w += v.w;
    }
    *(float4*)(ws2 + ((size_t)gid << 2)) = acc;
}

// Level-2 reduce + row op. mode 0: l2-normalize. mode 1: squash.
__global__ __launch_bounds__(256) void caps_reduce2(
    const float* __restrict__ ws2, float* __restrict__ dst, int mode)
{
    const int q = blockIdx.x * 256 + threadIdx.x;         // 0..8191
    float4 acc = make_float4(0.f, 0.f, 0.f, 0.f);
#pragma unroll
    for (int s = 0; s < NSLICE; ++s) {
        const float4 v = *(const float4*)(ws2 + ((size_t)s << 15) + (q << 2));
        acc.x += v.x; acc.y += v.y; acc.z += v.z; acc.w += v.w;
    }
    float s2 = acc.x * acc.x + acc.y * acc.y + acc.z * acc.z + acc.w * acc.w;
    s2 += __shfl_xor(s2, 1);
    s2 += __shfl_xor(s2, 2);
    s2 += __shfl_xor(s2, 4);
    float scale;
    if (mode == 0) {
        scale = rsqrtf(fmaxf(s2, 1e-12f));
    } else {
        scale = (s2 / (1.f + s2)) / sqrtf(s2 + 1e-7f);
    }
    float4 o;
    o.x = acc.x * scale; o.y = acc.y * scale;
    o.z = acc.z * scale; o.w = acc.w * scale;
    *(float4*)(dst + ((size_t)q << 2)) = o;
}

extern "C" void kernel_launch(void* const* d_in, const int* in_sizes, int n_in,
                              void* d_out, int out_size, void* d_ws, size_t ws_size,
                              hipStream_t stream)
{
    const float* u = (const float*)d_in[0];   // (32, 2048, 16)
    const float* W = (const float*)d_in[1];   // (2048, 16, 1024)
    float* out = (float*)d_out;               // (32, 32, 32)

    // ws layout: part (256*32768 fl = 32 MB) | ws2 (1 MB) | onorm (128 KB)
    float* part  = (float*)d_ws;
    float* ws2   = part + (size_t)NGRP * OSZ;
    float* onorm = ws2 + (size_t)NSLICE * OSZ;

    // onorm = 0 => logits 0 => softmax uniform 1/32 (exactly iteration 0)
    hipMemsetAsync(onorm, 0, (size_t)OSZ * sizeof(float), stream);

    for (int it = 0; it < 3; ++it) {
        caps_stage<<<2 * NGRP, 1024, 0, stream>>>(u, W, onorm, part);
        caps_reduce1<<<256, 256, 0, stream>>>(part, ws2);
        if (it < 2)
            caps_reduce2<<<32, 256, 0, stream>>>(ws2, onorm, 0);  // l2-normalize
        else
            caps_reduce2<<<32, 256, 0, stream>>>(ws2, out, 1);    // squash -> d_out
    }
}